// Round 3
// baseline (18.892 us; speedup 1.0000x reference)
//
#include <hip/hip_runtime.h>
#include <hip/hip_bf16.h>
#include <stdint.h>

// ---------------------------------------------------------------------------
// The reference collapses to:
//   qv  = prefix-recurrence over rotation_params (length E=1024)
//   h   = relu(ffn1_w @ qv + ffn1_b)        (F=4096)
//   y   = ffn2_w @ h + ffn2_b               (E=1024)
//   out[b] = dot(y, clf_w) + clf_b          (B=8 identical scalars)
// emb_table / input_ids / entangle_params / pos-encoding are dead code
// (x is overwritten by broadcast(qv) at the top of every block), and the
// NUM_BLOCKS loop is idempotent. mean over S of a constant-in-S tensor is
// the identity. All tensors are float32 (per reference dtypes).
// ---------------------------------------------------------------------------

// K1: qv[i] via prefix product.  q' = q + p - 2qp  <=>  r' = r*(1-2p), r = 1-2q.
__global__ void qv_kernel(const float* __restrict__ rot,
                          float* __restrict__ qv) {
    __shared__ float lds[1024];
    const int i = threadIdx.x;
    const float a = rot[i];
    const float b = rot[1024 + i];
    const float sa = sinf(0.5f * a), ca = cosf(0.5f * a);
    const float sb = sinf(0.5f * b), cb = cosf(0.5f * b);
    const float t0 = sb * ca;
    const float t1 = cb * sa;
    const float p = t0 * t0 + t1 * t1;
    lds[i] = 1.0f - 2.0f * p;
    __syncthreads();
    // inclusive Kogge-Stone prefix product over 1024 elements
    for (int off = 1; off < 1024; off <<= 1) {
        const float x = lds[i];
        const float v = (i >= off) ? lds[i - off] : 1.0f;
        __syncthreads();
        lds[i] = x * v;
        __syncthreads();
    }
    qv[i] = 0.5f * (1.0f - lds[i]);
}

// K2/K3: one wave per output row; C is a multiple of 512.
template <int C, bool RELU>
__global__ void matvec_kernel(const float* __restrict__ W,
                              const float* __restrict__ x,
                              const float* __restrict__ bias,
                              float* __restrict__ out) {
    const int wave = threadIdx.x >> 6;
    const int lane = threadIdx.x & 63;
    const int row  = blockIdx.x * 4 + wave;
    const float* wrow = W + (size_t)row * C;
    float sum = 0.0f;
#pragma unroll
    for (int it = 0; it < C / 512; ++it) {
        const int k = it * 512 + lane * 8;
        const float4 w0 = *reinterpret_cast<const float4*>(wrow + k);
        const float4 w1 = *reinterpret_cast<const float4*>(wrow + k + 4);
        const float4 x0 = *reinterpret_cast<const float4*>(x + k);
        const float4 x1 = *reinterpret_cast<const float4*>(x + k + 4);
        sum += w0.x * x0.x + w0.y * x0.y + w0.z * x0.z + w0.w * x0.w;
        sum += w1.x * x1.x + w1.y * x1.y + w1.z * x1.z + w1.w * x1.w;
    }
#pragma unroll
    for (int off = 32; off; off >>= 1) sum += __shfl_down(sum, off, 64);
    if (lane == 0) {
        float r = sum + bias[row];
        if (RELU) r = fmaxf(r, 0.0f);
        out[row] = r;
    }
}

// K4: scalar = dot(y, clf_w) + clf_b; broadcast to 8 f32 outputs.
__global__ void clf_kernel(const float* __restrict__ y,
                           const float* __restrict__ clf_w,
                           const float* __restrict__ clf_b,
                           float* __restrict__ out) {
    __shared__ float red[16];
    const int i    = threadIdx.x;          // 1024 threads
    const int lane = i & 63;
    const int wave = i >> 6;
    float s = y[i] * clf_w[i];
#pragma unroll
    for (int off = 32; off; off >>= 1) s += __shfl_down(s, off, 64);
    if (lane == 0) red[wave] = s;
    __syncthreads();
    if (wave == 0) {
        float v = (lane < 16) ? red[lane] : 0.0f;
#pragma unroll
        for (int off = 8; off; off >>= 1) v += __shfl_down(v, off, 64);
        if (lane == 0) {
            const float o = v + clf_b[0];
#pragma unroll
            for (int b = 0; b < 8; ++b) out[b] = o;
        }
    }
}

extern "C" void kernel_launch(void* const* d_in, const int* in_sizes, int n_in,
                              void* d_out, int out_size, void* d_ws, size_t ws_size,
                              hipStream_t stream) {
    (void)in_sizes; (void)n_in; (void)out_size; (void)ws_size;
    const float* rot    = (const float*)d_in[1];
    const float* ffn1_w = (const float*)d_in[4];
    const float* ffn1_b = (const float*)d_in[5];
    const float* ffn2_w = (const float*)d_in[6];
    const float* ffn2_b = (const float*)d_in[7];
    const float* clf_w  = (const float*)d_in[8];
    const float* clf_b  = (const float*)d_in[9];

    float* ws = (float*)d_ws;
    float* qv = ws;            // 1024 f32
    float* h  = ws + 1024;     // 4096 f32
    float* y  = ws + 5120;     // 1024 f32
    float* out = (float*)d_out;

    qv_kernel<<<1, 1024, 0, stream>>>(rot, qv);
    matvec_kernel<1024, true ><<<1024, 256, 0, stream>>>(ffn1_w, qv, ffn1_b, h);
    matvec_kernel<4096, false><<< 256, 256, 0, stream>>>(ffn2_w, h, ffn2_b, y);
    clf_kernel<<<1, 1024, 0, stream>>>(y, clf_w, clf_b, out);
}

// Round 4
// 16.581 us; speedup vs baseline: 1.1394x; 1.1394x over previous
//
#include <hip/hip_runtime.h>
#include <stdint.h>

// ---------------------------------------------------------------------------
// Reference collapses to a scalar:
//   qv  = prefix-recurrence over rotation_params             (E=1024)
//   h   = relu(ffn1_w @ qv + ffn1_b)                          (F=4096)
//   out[0..7] = clf_w . (ffn2_w @ h + ffn2_b) + clf_b         (8 copies)
// Reassociate:  clf_w . (ffn2_w @ h) = (ffn2_w^T clf_w) . h = w_eff . h,
// so w_eff (ffn2_w read) is independent of h (ffn1_w read) -> both 16.8 MB
// reads happen in ONE kernel phase. Block b owns f-slice [16b,16b+16):
// computes h[f] and w_eff[f] locally, emits one partial dot. No grid sync.
// ---------------------------------------------------------------------------

#define EDIM 1024
#define FDIM 4096
#define NBLK 256
#define TPB  512
#define FB   (FDIM / NBLK)   // 16 columns per block

__global__ __launch_bounds__(TPB) void fused_main(
    const float* __restrict__ rot,
    const float* __restrict__ ffn1_w,
    const float* __restrict__ ffn1_b,
    const float* __restrict__ ffn2_w,
    const float* __restrict__ clf_w,
    float* __restrict__ partials)
{
    __shared__ __align__(16) float qv_s[EDIM];
    __shared__ float sc[TPB];
    __shared__ float h_s[FB];
    __shared__ float red[TPB / 64];

    const int tid  = threadIdx.x;
    const int lane = tid & 63;
    const int wave = tid >> 6;
    const int f0   = blockIdx.x * FB;

    // ---- Phase A: qv, redundant per block. r = 1-2p; prefix product. ----
    float r0, r1;
    {
        const float a0 = rot[2 * tid],     b0 = rot[EDIM + 2 * tid];
        const float a1 = rot[2 * tid + 1], b1 = rot[EDIM + 2 * tid + 1];
        float sa = sinf(0.5f * a0), ca = cosf(0.5f * a0);
        float sb = sinf(0.5f * b0), cb = cosf(0.5f * b0);
        float t0 = sb * ca, t1 = cb * sa;
        r0 = 1.0f - 2.0f * (t0 * t0 + t1 * t1);
        sa = sinf(0.5f * a1); ca = cosf(0.5f * a1);
        sb = sinf(0.5f * b1); cb = cosf(0.5f * b1);
        t0 = sb * ca; t1 = cb * sa;
        r1 = 1.0f - 2.0f * (t0 * t0 + t1 * t1);
    }
    sc[tid] = r0 * r1;
    __syncthreads();
    // Kogge-Stone inclusive product scan over 512 thread-aggregates
    for (int off = 1; off < TPB; off <<= 1) {
        const float v = sc[tid];
        const float u = (tid >= off) ? sc[tid - off] : 1.0f;
        __syncthreads();
        sc[tid] = v * u;
        __syncthreads();
    }
    const float epre = (tid == 0) ? 1.0f : sc[tid - 1];
    qv_s[2 * tid]     = 0.5f * (1.0f - epre * r0);
    qv_s[2 * tid + 1] = 0.5f * (1.0f - epre * r0 * r1);
    __syncthreads();

    // ---- Phase B1: h for this block's 16 rows of ffn1_w ----
    // 8 waves x 2 rows each; one row = 1024 floats = 4 x (64 lanes x float4).
    const float4* qv4 = reinterpret_cast<const float4*>(qv_s);
#pragma unroll
    for (int q = 0; q < 2; ++q) {
        const int rloc = wave * 2 + q;                 // 0..15
        const int row  = f0 + rloc;
        const float* wrow = ffn1_w + (size_t)row * EDIM;
        float s = 0.0f;
#pragma unroll
        for (int it = 0; it < EDIM / 256; ++it) {      // 4
            const float4 w4 = *reinterpret_cast<const float4*>(wrow + it * 256 + lane * 4);
            const float4 q4 = qv4[it * 64 + lane];
            s += w4.x * q4.x + w4.y * q4.y + w4.z * q4.z + w4.w * q4.w;
        }
#pragma unroll
        for (int off = 32; off; off >>= 1) s += __shfl_down(s, off, 64);
        if (lane == 0) h_s[rloc] = fmaxf(s + ffn1_b[row], 0.0f);
    }

    // ---- Phase B2: w_eff partial for this block's 16 columns of ffn2_w ----
    // thread owns (col c, row-group g); no dependence on qv/h.
    const int c = tid & (FB - 1);   // 0..15
    const int g = tid >> 4;         // 0..31
    float acc = 0.0f;
#pragma unroll 8
    for (int e = g; e < EDIM; e += TPB / FB) {         // 32 iters, stride 32
        acc += clf_w[e] * ffn2_w[(size_t)e * FDIM + f0 + c];
    }

    __syncthreads();                                   // h_s ready
    // ---- Phase B3: partial = sum_t acc_t * h[c(t)] ----
    float v = acc * h_s[c];
#pragma unroll
    for (int off = 32; off; off >>= 1) v += __shfl_down(v, off, 64);
    if (lane == 0) red[wave] = v;
    __syncthreads();
    if (tid == 0) {
        float s = 0.0f;
#pragma unroll
        for (int w = 0; w < TPB / 64; ++w) s += red[w];
        partials[blockIdx.x] = s;
    }
}

// K2: out = sum(partials) + clf_w . ffn2_b + clf_b, broadcast to 8.
__global__ __launch_bounds__(256) void finalize(
    const float* __restrict__ partials,
    const float* __restrict__ ffn2_b,
    const float* __restrict__ clf_w,
    const float* __restrict__ clf_b,
    float* __restrict__ out)
{
    __shared__ float red[4];
    const int tid = threadIdx.x, lane = tid & 63, wave = tid >> 6;
    float s = partials[tid];
    const float4 cw = reinterpret_cast<const float4*>(clf_w)[tid];
    const float4 fb = reinterpret_cast<const float4*>(ffn2_b)[tid];
    s += cw.x * fb.x + cw.y * fb.y + cw.z * fb.z + cw.w * fb.w;
#pragma unroll
    for (int off = 32; off; off >>= 1) s += __shfl_down(s, off, 64);
    if (lane == 0) red[wave] = s;
    __syncthreads();
    if (tid == 0) {
        const float t = red[0] + red[1] + red[2] + red[3] + clf_b[0];
#pragma unroll
        for (int b = 0; b < 8; ++b) out[b] = t;
    }
}

extern "C" void kernel_launch(void* const* d_in, const int* in_sizes, int n_in,
                              void* d_out, int out_size, void* d_ws, size_t ws_size,
                              hipStream_t stream) {
    (void)in_sizes; (void)n_in; (void)out_size; (void)ws_size;
    const float* rot    = (const float*)d_in[1];
    const float* ffn1_w = (const float*)d_in[4];
    const float* ffn1_b = (const float*)d_in[5];
    const float* ffn2_w = (const float*)d_in[6];
    const float* ffn2_b = (const float*)d_in[7];
    const float* clf_w  = (const float*)d_in[8];
    const float* clf_b  = (const float*)d_in[9];

    float* partials = (float*)d_ws;      // 256 f32, all written before read
    float* out = (float*)d_out;

    fused_main<<<NBLK, TPB, 0, stream>>>(rot, ffn1_w, ffn1_b, ffn2_w, clf_w, partials);
    finalize<<<1, 256, 0, stream>>>(partials, ffn2_b, clf_w, clf_b, out);
}

// Round 5
// 12.594 us; speedup vs baseline: 1.5001x; 1.3166x over previous
//
#include <hip/hip_runtime.h>
#include <stdint.h>

// ---------------------------------------------------------------------------
// Reference collapses to a scalar:
//   r_i = cos(a_i)*cos(b_i)            [since p=(sb ca)^2+(cb sa)^2=(1-ca cb)/2]
//   qv_i = (1 - prod_{j<=i} r_j)/2
//   h   = relu(ffn1_w @ qv + ffn1_b)                          (F=4096)
//   out[0..7] = clf_w . (ffn2_w @ h + ffn2_b) + clf_b         (8 copies)
// Reassociated: clf_w.(ffn2_w@h) = (ffn2_w^T clf_w).h, so the ffn2_w read is
// independent of h -> both 16.8 MB weight reads stream in one kernel phase.
// Block owns f-slice [16l,16l+16): computes h-slice and w_eff-slice locally,
// emits one partial dot. All global loads issued BEFORE the qv scan so trig
// and barriers hide under HBM latency. XCD-swizzle puts adjacent column slabs
// (which share 128B lines of ffn2_w) on the same XCD L2.
// ---------------------------------------------------------------------------

#define EDIM 1024
#define FDIM 4096
#define NBLK 256
#define TPB  1024
#define FB   16

__global__ __launch_bounds__(TPB) void fused_main(
    const float* __restrict__ rot,
    const float* __restrict__ ffn1_w,
    const float* __restrict__ ffn1_b,
    const float* __restrict__ ffn2_w,
    const float* __restrict__ clf_w,
    float* __restrict__ partials)
{
    __shared__ __align__(16) float qv_s[EDIM];
    __shared__ float wagg[16];
    __shared__ float h_s[FB];
    __shared__ float red[16];

    const int tid  = threadIdx.x;
    const int lane = tid & 63;
    const int wave = tid >> 6;                    // 0..15
    const int d    = blockIdx.x;
    const int l    = ((d & 7) << 5) | (d >> 3);   // XCD-aware slab swizzle
    const int f0   = l * FB;

    // ---- issue ALL independent global loads first (hide scan under them) ----
    // B1 weights: wave w owns ffn1_w row (f0+w); 4 x float4 per lane.
    const float* w1row = ffn1_w + (size_t)(f0 + wave) * EDIM;
    float4 w1[4];
#pragma unroll
    for (int it = 0; it < 4; ++it)
        w1[it] = *reinterpret_cast<const float4*>(w1row + it * 256 + lane * 4);

    // B2 weights: thread owns cols f0+4*c4..+3, rows e = g + 256k.
    const int c4 = tid & 3;
    const int g  = tid >> 2;                      // 0..255
    float4 w2[4]; float cw[4];
#pragma unroll
    for (int k = 0; k < 4; ++k) {
        const int e = g + 256 * k;
        w2[k] = *reinterpret_cast<const float4*>(ffn2_w + (size_t)e * FDIM + f0 + 4 * c4);
        cw[k] = clf_w[e];
    }

    const float a = rot[tid];
    const float b = rot[EDIM + tid];

    // ---- qv: r = cos(a)*cos(b); prefix product over 1024 elems ----
    const float r = cosf(a) * cosf(b);
    float v = r;                                   // wave-inclusive scan
#pragma unroll
    for (int off = 1; off < 64; off <<= 1) {
        const float u = __shfl_up(v, off, 64);
        if (lane >= off) v *= u;
    }
    if (lane == 63) wagg[wave] = v;
    __syncthreads();
    float pre = 1.0f;
#pragma unroll
    for (int w = 0; w < 16; ++w)
        if (w < wave) pre *= wagg[w];
    qv_s[tid] = 0.5f * (1.0f - pre * v);
    __syncthreads();

    // ---- w_eff partial (independent of qv; loads already in flight) ----
    float4 acc4 = make_float4(0.f, 0.f, 0.f, 0.f);
#pragma unroll
    for (int k = 0; k < 4; ++k) {
        acc4.x += cw[k] * w2[k].x;
        acc4.y += cw[k] * w2[k].y;
        acc4.z += cw[k] * w2[k].z;
        acc4.w += cw[k] * w2[k].w;
    }

    // ---- h[f0+wave] = relu(row . qv + b) ----
    const float4* qv4 = reinterpret_cast<const float4*>(qv_s);
    float s = 0.f;
#pragma unroll
    for (int it = 0; it < 4; ++it) {
        const float4 q4 = qv4[it * 64 + lane];
        s += w1[it].x * q4.x + w1[it].y * q4.y + w1[it].z * q4.z + w1[it].w * q4.w;
    }
#pragma unroll
    for (int off = 32; off; off >>= 1) s += __shfl_down(s, off, 64);
    if (lane == 0) h_s[wave] = fmaxf(s + ffn1_b[f0 + wave], 0.0f);
    __syncthreads();

    // ---- partial = sum_t acc4 . h[4c4..4c4+3] ----
    float p = acc4.x * h_s[4 * c4]     + acc4.y * h_s[4 * c4 + 1]
            + acc4.z * h_s[4 * c4 + 2] + acc4.w * h_s[4 * c4 + 3];
#pragma unroll
    for (int off = 32; off; off >>= 1) p += __shfl_down(p, off, 64);
    if (lane == 0) red[wave] = p;
    __syncthreads();
    if (tid == 0) {
        float t = 0.f;
#pragma unroll
        for (int w = 0; w < 16; ++w) t += red[w];
        partials[l] = t;
    }
}

// K2: out = sum(partials) + clf_w . ffn2_b + clf_b, broadcast to 8.
__global__ __launch_bounds__(256) void finalize(
    const float* __restrict__ partials,
    const float* __restrict__ ffn2_b,
    const float* __restrict__ clf_w,
    const float* __restrict__ clf_b,
    float* __restrict__ out)
{
    __shared__ float red[4];
    const int tid = threadIdx.x, lane = tid & 63, wave = tid >> 6;
    float s = partials[tid];
    const float4 cwv = reinterpret_cast<const float4*>(clf_w)[tid];
    const float4 fbv = reinterpret_cast<const float4*>(ffn2_b)[tid];
    s += cwv.x * fbv.x + cwv.y * fbv.y + cwv.z * fbv.z + cwv.w * fbv.w;
#pragma unroll
    for (int off = 32; off; off >>= 1) s += __shfl_down(s, off, 64);
    if (lane == 0) red[wave] = s;
    __syncthreads();
    if (tid == 0) {
        const float t = red[0] + red[1] + red[2] + red[3] + clf_b[0];
#pragma unroll
        for (int b = 0; b < 8; ++b) out[b] = t;
    }
}

extern "C" void kernel_launch(void* const* d_in, const int* in_sizes, int n_in,
                              void* d_out, int out_size, void* d_ws, size_t ws_size,
                              hipStream_t stream) {
    (void)in_sizes; (void)n_in; (void)out_size; (void)ws_size;
    const float* rot    = (const float*)d_in[1];
    const float* ffn1_w = (const float*)d_in[4];
    const float* ffn1_b = (const float*)d_in[5];
    const float* ffn2_w = (const float*)d_in[6];
    const float* ffn2_b = (const float*)d_in[7];
    const float* clf_w  = (const float*)d_in[8];
    const float* clf_b  = (const float*)d_in[9];

    float* partials = (float*)d_ws;      // 256 f32, fully rewritten each call
    float* out = (float*)d_out;

    fused_main<<<NBLK, TPB, 0, stream>>>(rot, ffn1_w, ffn1_b, ffn2_w, clf_w, partials);
    finalize<<<1, 256, 0, stream>>>(partials, ffn2_b, clf_w, clf_b, out);
}